// Round 7
// baseline (82.767 us; speedup 1.0000x reference)
//
#include <hip/hip_runtime.h>
#include <math.h>

// LSTM autoencoder, single timestep, h0=c0=0.
// => whh unused; f-gate unused. Fused single kernel, 7 phases.
// FENCE-FREE grid barrier: h exchanged via agent-scope relaxed atomics
// (coherent point, no L2 writeback/invalidate); weights are read-only so
// stale caches are harmless. Hierarchical counters, relaxed polls.
// 256 blocks x 512 threads = 2048 waves, 1 block/CU (plain launch).

#define NB 256
#define NT 512
#define GRPSZ 8
#define NGRP (NB / GRPSZ)                  // 32
#define PAD 32                             // u32 per line (128 B)
#define PHASE_U32 ((2 * NGRP + 1) * PAD)   // 2080
#define BAR_U32 16384                      // 64 KB barrier region

typedef float v4f __attribute__((ext_vector_type(4)));

__device__ __forceinline__ float sigmoidf_(float v) {
    return 1.0f / (1.0f + expf(-v));
}

__device__ __forceinline__ float wred(float v) {
    #pragma unroll
    for (int off = 32; off > 0; off >>= 1) v += __shfl_xor(v, off, 64);
    return v;
}

__device__ __forceinline__ void st_agent(float* p, float v) {
    __hip_atomic_store(p, v, __ATOMIC_RELAXED, __HIP_MEMORY_SCOPE_AGENT);
}

// Fence-free hierarchical grid barrier (fresh counters per barrier).
__device__ __forceinline__ void gbar(unsigned* base) {
    __syncthreads();                      // drains vmcnt: h-stores complete
    if (threadIdx.x == 0) {
        const unsigned bid = blockIdx.x;
        const unsigned gid = bid >> 3;
        unsigned* garr = base + (size_t)gid * PAD;
        unsigned* ggo  = base + (size_t)(NGRP + gid) * PAD;
        unsigned* cent = base + (size_t)(2 * NGRP) * PAD;
        __hip_atomic_fetch_add(garr, 1u, __ATOMIC_RELEASE, __HIP_MEMORY_SCOPE_AGENT);
        if ((bid & 7) == 0) {
            while (__hip_atomic_load(garr, __ATOMIC_RELAXED, __HIP_MEMORY_SCOPE_AGENT) < GRPSZ)
                __builtin_amdgcn_s_sleep(1);
            __hip_atomic_fetch_add(cent, 1u, __ATOMIC_RELAXED, __HIP_MEMORY_SCOPE_AGENT);
            while (__hip_atomic_load(cent, __ATOMIC_RELAXED, __HIP_MEMORY_SCOPE_AGENT) < NGRP)
                __builtin_amdgcn_s_sleep(2);
            __hip_atomic_store(ggo, 1u, __ATOMIC_RELAXED, __HIP_MEMORY_SCOPE_AGENT);
        } else {
            while (__hip_atomic_load(ggo, __ATOMIC_RELAXED, __HIP_MEMORY_SCOPE_AGENT) == 0)
                __builtin_amdgcn_s_sleep(2);
        }
    }
    __builtin_amdgcn_sched_barrier(0);
    __syncthreads();
}

// Stage phase input into LDS. ATOMIC=true reads via agent-scope atomics
// (bypasses possibly-stale L1/L2 for cross-block data).
template<int N, bool ATOMIC>
__device__ __forceinline__ void stage(const float* __restrict__ g, float* xs) {
    if constexpr (ATOMIC) {
        for (int i = threadIdx.x * 2; i < N; i += NT * 2) {
            unsigned long long u = __hip_atomic_load(
                (const unsigned long long*)(g + i),
                __ATOMIC_RELAXED, __HIP_MEMORY_SCOPE_AGENT);
            union { unsigned long long u; float f[2]; } c; c.u = u;
            xs[i] = c.f[0]; xs[i + 1] = c.f[1];
        }
    } else {
        for (int i = threadIdx.x * 4; i < N; i += NT * 4)
            *reinterpret_cast<v4f*>(xs + i) = *reinterpret_cast<const v4f*>(g + i);
    }
    __syncthreads();
}

// CLEN multiple of 256.
template<int CLEN>
__device__ __forceinline__ void dot3(const float* __restrict__ wi,
                                     const float* __restrict__ wg,
                                     const float* __restrict__ wo,
                                     const float* __restrict__ xs,
                                     int lane, float& si, float& sg, float& so) {
    si = 0.f; sg = 0.f; so = 0.f;
    #pragma unroll 4
    for (int c0 = 0; c0 < CLEN; c0 += 256) {
        const int c = c0 + lane * 4;
        const v4f xv = *reinterpret_cast<const v4f*>(xs + c);
        const v4f av = *reinterpret_cast<const v4f*>(wi + c);
        const v4f gv = *reinterpret_cast<const v4f*>(wg + c);
        const v4f ov = *reinterpret_cast<const v4f*>(wo + c);
        si += av.x * xv.x + av.y * xv.y + av.z * xv.z + av.w * xv.w;
        sg += gv.x * xv.x + gv.y * xv.y + gv.z * xv.z + gv.w * xv.w;
        so += ov.x * xv.x + ov.y * xv.y + ov.z * xv.z + ov.w * xv.w;
    }
}

__device__ __forceinline__ void epi(float si, float sg, float so,
                                    const float* __restrict__ bi,
                                    const float* __restrict__ bh,
                                    int j, int dh, float* __restrict__ h) {
    const float gi = si + bi[j]          + bh[j];
    const float gg = sg + bi[j + 2 * dh] + bh[j + 2 * dh];
    const float go = so + bi[j + 3 * dh] + bh[j + 3 * dh];
    st_agent(h + j, sigmoidf_(go) * tanhf(sigmoidf_(gi) * tanhf(gg)));
}

// One LSTM phase over 2048 waves. SPLIT waves share a row (column split).
template<int C, int SPLIT>
__device__ __forceinline__ void cell(const float* __restrict__ w,
                                     const float* __restrict__ bi,
                                     const float* __restrict__ bh,
                                     const float* __restrict__ xs,
                                     float* __restrict__ h,
                                     int dh, int wv, int wl, int lane,
                                     float (*red)[3]) {
    constexpr int CL = C / SPLIT;
    const int j = wv / SPLIT;
    const int part = wv % SPLIT;
    const int off = part * CL;
    const float* wi = w + (size_t)j * C + off;
    const float* wg = w + ((size_t)j + 2u * (size_t)dh) * C + off;
    const float* wo = w + ((size_t)j + 3u * (size_t)dh) * C + off;
    float si, sg, so;
    dot3<CL>(wi, wg, wo, xs + off, lane, si, sg, so);
    si = wred(si); sg = wred(sg); so = wred(so);
    if constexpr (SPLIT > 1) {
        if (lane == 0) { red[wl][0] = si; red[wl][1] = sg; red[wl][2] = so; }
        __syncthreads();
        if (part == 0 && lane == 0) {
            #pragma unroll
            for (int k = 1; k < SPLIT; ++k) {
                si += red[wl + k][0]; sg += red[wl + k][1]; so += red[wl + k][2];
            }
            epi(si, sg, so, bi, bh, j, dh, h);
        }
    } else {
        if (lane == 0) epi(si, sg, so, bi, bh, j, dh, h);
    }
}

// Final linear: 4096 rows, 2 rows/wave, C=2048. Plain stores to d_out.
__device__ __forceinline__ void linear2(const float* __restrict__ w,
                                        const float* __restrict__ b,
                                        const float* __restrict__ xs,
                                        float* __restrict__ y,
                                        int wv, int lane) {
    const int j0 = wv, j1 = wv + 2048;
    const float* w0r = w + (size_t)j0 * 2048;
    const float* w1r = w + (size_t)j1 * 2048;
    float s0 = 0.f, s1 = 0.f;
    #pragma unroll 4
    for (int c0 = 0; c0 < 2048; c0 += 256) {
        const int c = c0 + lane * 4;
        const v4f xv = *reinterpret_cast<const v4f*>(xs + c);
        const v4f a  = *reinterpret_cast<const v4f*>(w0r + c);
        const v4f d  = *reinterpret_cast<const v4f*>(w1r + c);
        s0 += a.x * xv.x + a.y * xv.y + a.z * xv.z + a.w * xv.w;
        s1 += d.x * xv.x + d.y * xv.y + d.z * xv.z + d.w * xv.w;
    }
    s0 = wred(s0); s1 = wred(s1);
    if (lane == 0) { y[j0] = s0 + b[j0]; y[j1] = s1 + b[j1]; }
}

struct Params {
    const float *x;
    const float *w0, *bi0, *bh0;  // e1l0: 2048 rows, C=4096
    const float *w1, *bi1, *bh1;  // e1l1: 2048, C=2048
    const float *w2, *bi2, *bh2;  // e2:   1024, C=2048
    const float *w3, *bi3, *bh3;  // d1l0: 1024, C=1024
    const float *w4, *bi4, *bh4;  // d1l1: 1024, C=1024
    const float *w5, *bi5, *bh5;  // d2:   2048, C=1024
    const float *ow, *ob;         // out:  4096, C=2048
    float *out;
    float *ws;
};

__global__ __launch_bounds__(NT, 1) void fused_lstm_ae(Params p) {
    __shared__ float xs[4096];
    __shared__ float red[8][3];
    const int lane = threadIdx.x & 63;
    const int wl = threadIdx.x >> 6;
    const int wv = (int)blockIdx.x * 8 + wl;

    unsigned* bar = (unsigned*)p.ws;      // 64 KB, zeroed per call
    float* h1 = p.ws + BAR_U32;           // 2048
    float* h2 = h1 + 2048;                // 2048
    float* z  = h2 + 2048;                // 1024
    float* h3 = z  + 1024;                // 1024
    float* h4 = h3 + 1024;                // 1024
    float* h5 = h4 + 1024;                // 2048

    stage<4096, false>(p.x, xs);
    cell<4096, 1>(p.w0, p.bi0, p.bh0, xs, h1, 2048, wv, wl, lane, red);
    gbar(bar + 0 * PHASE_U32);
    stage<2048, true>(h1, xs);
    cell<2048, 1>(p.w1, p.bi1, p.bh1, xs, h2, 2048, wv, wl, lane, red);
    gbar(bar + 1 * PHASE_U32);
    stage<2048, true>(h2, xs);
    cell<2048, 2>(p.w2, p.bi2, p.bh2, xs, z, 1024, wv, wl, lane, red);
    gbar(bar + 2 * PHASE_U32);
    stage<1024, true>(z, xs);
    cell<1024, 2>(p.w3, p.bi3, p.bh3, xs, h3, 1024, wv, wl, lane, red);
    gbar(bar + 3 * PHASE_U32);
    stage<1024, true>(h3, xs);
    cell<1024, 2>(p.w4, p.bi4, p.bh4, xs, h4, 1024, wv, wl, lane, red);
    gbar(bar + 4 * PHASE_U32);
    stage<1024, true>(h4, xs);
    cell<1024, 1>(p.w5, p.bi5, p.bh5, xs, h5, 2048, wv, wl, lane, red);
    gbar(bar + 5 * PHASE_U32);
    stage<2048, true>(h5, xs);
    linear2(p.ow, p.ob, xs, p.out, wv, lane);
}

extern "C" void kernel_launch(void* const* d_in, const int* in_sizes, int n_in,
                              void* d_out, int out_size, void* d_ws, size_t ws_size,
                              hipStream_t stream)
{
    Params p;
    p.x   = (const float*)d_in[0];
    p.w0  = (const float*)d_in[1];
    p.bi0 = (const float*)d_in[3];
    p.bh0 = (const float*)d_in[4];
    p.w1  = (const float*)d_in[5];
    p.bi1 = (const float*)d_in[7];
    p.bh1 = (const float*)d_in[8];
    p.w2  = (const float*)d_in[9];
    p.bi2 = (const float*)d_in[11];
    p.bh2 = (const float*)d_in[12];
    p.w3  = (const float*)d_in[13];
    p.bi3 = (const float*)d_in[15];
    p.bh3 = (const float*)d_in[16];
    p.w4  = (const float*)d_in[17];
    p.bi4 = (const float*)d_in[19];
    p.bh4 = (const float*)d_in[20];
    p.w5  = (const float*)d_in[21];
    p.bi5 = (const float*)d_in[23];
    p.bh5 = (const float*)d_in[24];
    p.ow  = (const float*)d_in[25];
    p.ob  = (const float*)d_in[26];
    p.out = (float*)d_out;
    p.ws  = (float*)d_ws;

    // Zero barrier counters (must not persist across graph replays).
    hipMemsetAsync(d_ws, 0, BAR_U32 * sizeof(unsigned), stream);

    fused_lstm_ae<<<NB, NT, 0, stream>>>(p);
}